// Round 2
// baseline (1936.897 us; speedup 1.0000x reference)
//
#include <hip/hip_runtime.h>

// NeuralFieldCosmo: per-edge MLP(3->32->32->256, LN+ReLU, tanh) -> [16x16] W,
// gather f = edge_features[in_edges], out_ch[o] = sum_i f[i]*W[o][i],
// scatter-mean over out_edges into N rows.
//
// R2: replace 16M f32 device-scope atomics (4.4 GB TCC traffic, round-1
// bottleneck) with CSR two-phase scatter: hist -> scan -> main(stream out_ch
// + bucket placement) -> per-node reduce.

constexpr float LN_EPS   = 1e-5f;
constexpr float LOG2E_X2 = 2.8853900817779268f;  // 2*log2(e)

__device__ __forceinline__ float fast_tanh(float x) {
  // tanh(x) = 1 - 2/(exp(2x)+1); exp(2x) = 2^(2x*log2e). Handles +-inf correctly.
  float e = __builtin_amdgcn_exp2f(x * LOG2E_X2);
  return 1.0f - 2.0f * __builtin_amdgcn_rcpf(e + 1.0f);
}

__device__ __forceinline__ void ln_relu(float* h, const float* __restrict__ g,
                                        const float* __restrict__ be) {
  float m = 0.f;
#pragma unroll
  for (int j = 0; j < 32; ++j) m += h[j];
  m *= (1.0f / 32.0f);
  float v = 0.f;
#pragma unroll
  for (int j = 0; j < 32; ++j) { float d = h[j] - m; v += d * d; }
  v *= (1.0f / 32.0f);
  const float rs = rsqrtf(v + LN_EPS);
#pragma unroll
  for (int j = 0; j < 32; ++j) {
    float y = (h[j] - m) * rs * g[j] + be[j];
    h[j] = y > 0.f ? y : 0.f;
  }
}

// ---------------- CSR build ----------------

__global__ void nf_hist(const int* __restrict__ out_edges, int* __restrict__ counts, int E) {
  int stride = gridDim.x * blockDim.x;
  for (int e = blockIdx.x * blockDim.x + threadIdx.x; e < E; e += stride)
    atomicAdd(&counts[out_edges[e]], 1);
}

// single-block exclusive scan of counts[0..n) -> offsets, cursor
__global__ __launch_bounds__(1024)
void nf_scan(const int* __restrict__ counts, int* __restrict__ offsets,
             int* __restrict__ cursor, int n) {
  __shared__ int part[1024];
  const int tid = threadIdx.x;
  const int per = (n + 1023) >> 10;
  const int s0 = tid * per;
  const int s1 = min(s0 + per, n);
  int s = 0;
  for (int i = s0; i < s1; ++i) s += counts[i];
  part[tid] = s;
  __syncthreads();
  // Hillis-Steele inclusive scan
  for (int d = 1; d < 1024; d <<= 1) {
    int v = (tid >= d) ? part[tid - d] : 0;
    __syncthreads();
    part[tid] += v;
    __syncthreads();
  }
  int run = (tid > 0) ? part[tid - 1] : 0;  // exclusive
  for (int i = s0; i < s1; ++i) {
    offsets[i] = run;
    cursor[i]  = run;
    run += counts[i];
  }
}

// ---------------- main compute ----------------
// SCATTER_MODE: 0 = CSR (write out_ch + bucket), 1 = direct atomics (fallback)

template <int SCATTER_MODE>
__global__ __launch_bounds__(256, 4)
void nf_main(const int* __restrict__ in_edges,
             const int* __restrict__ out_edges,
             const float* __restrict__ edge_features,
             const float* __restrict__ coords,
             const float* __restrict__ W1, const float* __restrict__ b1,
             const float* __restrict__ g1, const float* __restrict__ be1,
             const float* __restrict__ W2, const float* __restrict__ b2,
             const float* __restrict__ g2, const float* __restrict__ be2,
             const float* __restrict__ W3, const float* __restrict__ b3,
             float* __restrict__ out_ch,   // CSR: [E][16]   | fallback: sums (d_out)
             int* __restrict__ bucket,     // CSR: [E]       | fallback: counts
             int* __restrict__ cursor,     // CSR: [N]       | fallback: unused
             int E)
{
  __shared__ float sW1[96];
  __shared__ float sb1[32], sg1[32], sbe1[32];
  __shared__ float sW2T[32 * 32];          // sW2T[j*32+k] = W2[k][j]
  __shared__ float sb2[32], sg2[32], sbe2[32];
  __shared__ float sW3T[256 * 32];         // sW3T[j*32+k] = W3[k][j]
  __shared__ float sb3[256];

  const int t = threadIdx.x;
  if (t < 96) sW1[t] = W1[t];
  if (t < 32) {
    sb1[t] = b1[t]; sg1[t] = g1[t]; sbe1[t] = be1[t];
    sb2[t] = b2[t]; sg2[t] = g2[t]; sbe2[t] = be2[t];
  }
  sb3[t] = b3[t];
#pragma unroll
  for (int i = 0; i < 4; ++i) {
    int idx = i * 256 + t;                 // idx = j*32+k
    sW2T[idx] = W2[(idx & 31) * 32 + (idx >> 5)];
  }
#pragma unroll
  for (int i = 0; i < 32; ++i) {
    int idx = i * 256 + t;                 // idx = j*32+k
    sW3T[idx] = W3[(idx & 31) * 256 + (idx >> 5)];
  }
  __syncthreads();

  const int stride = gridDim.x * blockDim.x;
  for (int e = blockIdx.x * blockDim.x + t; e < E; e += stride) {
    const float x0 = coords[3 * e + 0];
    const float x1 = coords[3 * e + 1];
    const float x2 = coords[3 * e + 2];

    // Layer 1: 3 -> 32, LN, ReLU
    float h[32];
#pragma unroll
    for (int j = 0; j < 32; ++j)
      h[j] = sb1[j] + x0 * sW1[j] + x1 * sW1[32 + j] + x2 * sW1[64 + j];
    ln_relu(h, sg1, sbe1);

    // Layer 2: 32 -> 32, LN, ReLU
    float h2[32];
#pragma unroll
    for (int j = 0; j < 32; ++j) {
      float a = sb2[j];
      const float4* r = (const float4*)&sW2T[j * 32];
#pragma unroll
      for (int k = 0; k < 8; ++k) {
        float4 w = r[k];
        a += h[4 * k + 0] * w.x + h[4 * k + 1] * w.y +
             h[4 * k + 2] * w.z + h[4 * k + 3] * w.w;
      }
      h2[j] = a;
    }
    ln_relu(h2, sg2, sbe2);

    // Gather f (16 floats)
    const int ie = in_edges[e];
    const float4* fp = (const float4*)(edge_features + (size_t)ie * 16);
    float4 f0 = fp[0], f1 = fp[1], f2 = fp[2], f3 = fp[3];
    float f[16] = {f0.x, f0.y, f0.z, f0.w, f1.x, f1.y, f1.z, f1.w,
                   f2.x, f2.y, f2.z, f2.w, f3.x, f3.y, f3.z, f3.w};

    const int oe = out_edges[e];
    if (SCATTER_MODE == 0) {
      int pos = atomicAdd(&cursor[oe], 1);
      bucket[pos] = e;
    }

    // Layer 3 (32 -> 256) fused with tanh + per-edge matvec
    for (int o = 0; o < 16; ++o) {         // runtime loop: scalar accumulator
      float a = 0.f;
#pragma unroll
      for (int i = 0; i < 16; ++i) {
        const int j = o * 16 + i;
        const float4* r = (const float4*)&sW3T[j * 32];
        float acc = sb3[j];
#pragma unroll
        for (int k = 0; k < 8; ++k) {
          float4 w = r[k];
          acc += h2[4 * k + 0] * w.x + h2[4 * k + 1] * w.y +
                 h2[4 * k + 2] * w.z + h2[4 * k + 3] * w.w;
        }
        a += f[i] * fast_tanh(acc);
      }
      if (SCATTER_MODE == 0) {
        out_ch[(size_t)e * 16 + o] = a;    // streamed, no atomics
      } else {
        atomicAdd(&out_ch[(size_t)oe * 16 + o], a);
      }
    }
    if (SCATTER_MODE == 1) atomicAdd(&bucket[oe], 1);
  }
}

// ---------------- per-node reduce (CSR path) ----------------

__global__ __launch_bounds__(256)
void nf_reduce(const float* __restrict__ out_ch, const int* __restrict__ bucket,
               const int* __restrict__ counts, const int* __restrict__ offsets,
               float* __restrict__ out, int N) {
  const int gid = blockIdx.x * 16 + (threadIdx.x >> 4);  // node
  const int o   = threadIdx.x & 15;                      // channel
  if (gid >= N) return;
  const int deg = counts[gid];
  const int off = offsets[gid];
  float acc = 0.f;
  for (int d = 0; d < deg; ++d) {
    int eid = bucket[off + d];
    acc += out_ch[(size_t)eid * 16 + o];
  }
  out[(size_t)gid * 16 + o] = acc / fmaxf((float)deg, 1.0f);
}

// fallback divide
__global__ void nf_final(float* __restrict__ out, const int* __restrict__ counts, int n) {
  int i = blockIdx.x * blockDim.x + threadIdx.x;
  if (i < n) {
    float c = (float)counts[i >> 4];
    out[i] = out[i] / fmaxf(c, 1.0f);
  }
}

extern "C" void kernel_launch(void* const* d_in, const int* in_sizes, int n_in,
                              void* d_out, int out_size, void* d_ws, size_t ws_size,
                              hipStream_t stream) {
  const int*   in_edges  = (const int*)d_in[0];
  const int*   out_edges = (const int*)d_in[1];
  const float* ef        = (const float*)d_in[2];
  const float* coords    = (const float*)d_in[3];
  const float* W1  = (const float*)d_in[4];
  const float* b1  = (const float*)d_in[5];
  const float* g1  = (const float*)d_in[6];
  const float* be1 = (const float*)d_in[7];
  const float* W2  = (const float*)d_in[8];
  const float* b2  = (const float*)d_in[9];
  const float* g2  = (const float*)d_in[10];
  const float* be2 = (const float*)d_in[11];
  const float* W3  = (const float*)d_in[12];
  const float* b3  = (const float*)d_in[13];

  const int E = in_sizes[0];
  const int N = in_sizes[2] / 16;
  float* out = (float*)d_out;

  // workspace layout (CSR path)
  const size_t need = ((size_t)E * 16 + (size_t)E + 3 * (size_t)N) * 4;

  if (ws_size >= need) {
    float* out_ch  = (float*)d_ws;
    int*   bucket  = (int*)(out_ch + (size_t)E * 16);
    int*   counts  = bucket + E;
    int*   offsets = counts + N;
    int*   cursor  = offsets + N;

    hipMemsetAsync(counts, 0, (size_t)N * sizeof(int), stream);
    nf_hist<<<1024, 256, 0, stream>>>(out_edges, counts, E);
    nf_scan<<<1, 1024, 0, stream>>>(counts, offsets, cursor, N);
    nf_main<0><<<2048, 256, 0, stream>>>(in_edges, out_edges, ef, coords,
                                         W1, b1, g1, be1, W2, b2, g2, be2, W3, b3,
                                         out_ch, bucket, cursor, E);
    nf_reduce<<<(N + 15) / 16, 256, 0, stream>>>(out_ch, bucket, counts, offsets, out, N);
  } else {
    // fallback: round-1 direct-atomic path
    int* counts = (int*)d_ws;
    hipMemsetAsync(out, 0, (size_t)out_size * sizeof(float), stream);
    hipMemsetAsync(counts, 0, (size_t)N * sizeof(int), stream);
    nf_main<1><<<2048, 256, 0, stream>>>(in_edges, out_edges, ef, coords,
                                         W1, b1, g1, be1, W2, b2, g2, be2, W3, b3,
                                         out, counts, nullptr, E);
    nf_final<<<(out_size + 255) / 256, 256, 0, stream>>>(out, counts, out_size);
  }
}

// Round 3
// 1044.624 us; speedup vs baseline: 1.8542x; 1.8542x over previous
//
#include <hip/hip_runtime.h>

// NeuralFieldCosmo: per-edge MLP(3->32->32->256, LN+ReLU, tanh) -> [16x16] W,
// gather f = edge_features[in_edges], out_ch[o] = sum_i f[i]*W[o][i],
// scatter-mean over out_edges into N rows.
//
// R3: fix register spilling. R1/R2 both showed VGPR_Count=64 with ~4.5 GB
// HBM traffic (live set ~100 regs -> scratch spill in the 16x inner loop).
// launch_bounds(256,2) raises the VGPR cap to 256; unroll pragmas bound
// scheduler load-hoisting pressure. CSR scatter kept from R2.

constexpr float LN_EPS   = 1e-5f;
constexpr float LOG2E_X2 = 2.8853900817779268f;  // 2*log2(e)

__device__ __forceinline__ float fast_tanh(float x) {
  // tanh(x) = 1 - 2/(exp(2x)+1); exp(2x) = 2^(2x*log2e). Handles +-inf correctly.
  float e = __builtin_amdgcn_exp2f(x * LOG2E_X2);
  return 1.0f - 2.0f * __builtin_amdgcn_rcpf(e + 1.0f);
}

__device__ __forceinline__ void ln_relu(float* h, const float* __restrict__ g,
                                        const float* __restrict__ be) {
  float m = 0.f;
#pragma unroll
  for (int j = 0; j < 32; ++j) m += h[j];
  m *= (1.0f / 32.0f);
  float v = 0.f;
#pragma unroll
  for (int j = 0; j < 32; ++j) { float d = h[j] - m; v += d * d; }
  v *= (1.0f / 32.0f);
  const float rs = rsqrtf(v + LN_EPS);
#pragma unroll
  for (int j = 0; j < 32; ++j) {
    float y = (h[j] - m) * rs * g[j] + be[j];
    h[j] = y > 0.f ? y : 0.f;
  }
}

// ---------------- CSR build ----------------

__global__ void nf_hist(const int* __restrict__ out_edges, int* __restrict__ counts, int E) {
  int stride = gridDim.x * blockDim.x;
  for (int e = blockIdx.x * blockDim.x + threadIdx.x; e < E; e += stride)
    atomicAdd(&counts[out_edges[e]], 1);
}

// single-block exclusive scan of counts[0..n) -> offsets, cursor
__global__ __launch_bounds__(1024)
void nf_scan(const int* __restrict__ counts, int* __restrict__ offsets,
             int* __restrict__ cursor, int n) {
  __shared__ int part[1024];
  const int tid = threadIdx.x;
  const int per = (n + 1023) >> 10;
  const int s0 = tid * per;
  const int s1 = min(s0 + per, n);
  int s = 0;
  for (int i = s0; i < s1; ++i) s += counts[i];
  part[tid] = s;
  __syncthreads();
  // Hillis-Steele inclusive scan
  for (int d = 1; d < 1024; d <<= 1) {
    int v = (tid >= d) ? part[tid - d] : 0;
    __syncthreads();
    part[tid] += v;
    __syncthreads();
  }
  int run = (tid > 0) ? part[tid - 1] : 0;  // exclusive
  for (int i = s0; i < s1; ++i) {
    offsets[i] = run;
    cursor[i]  = run;
    run += counts[i];
  }
}

// ---------------- main compute ----------------
// SCATTER_MODE: 0 = CSR (write out_ch + bucket), 1 = direct atomics (fallback)

template <int SCATTER_MODE>
__global__ __launch_bounds__(256, 2)   // cap 256 VGPR: live set ~100+, do NOT spill
void nf_main(const int* __restrict__ in_edges,
             const int* __restrict__ out_edges,
             const float* __restrict__ edge_features,
             const float* __restrict__ coords,
             const float* __restrict__ W1, const float* __restrict__ b1,
             const float* __restrict__ g1, const float* __restrict__ be1,
             const float* __restrict__ W2, const float* __restrict__ b2,
             const float* __restrict__ g2, const float* __restrict__ be2,
             const float* __restrict__ W3, const float* __restrict__ b3,
             float* __restrict__ out_ch,   // CSR: [E][16]   | fallback: sums (d_out)
             int* __restrict__ bucket,     // CSR: [E]       | fallback: counts
             int* __restrict__ cursor,     // CSR: [N]       | fallback: unused
             int E)
{
  __shared__ float sW1[96];
  __shared__ float sb1[32], sg1[32], sbe1[32];
  __shared__ float sW2T[32 * 32];          // sW2T[j*32+k] = W2[k][j]
  __shared__ float sb2[32], sg2[32], sbe2[32];
  __shared__ float sW3T[256 * 32];         // sW3T[j*32+k] = W3[k][j]
  __shared__ float sb3[256];

  const int t = threadIdx.x;
  if (t < 96) sW1[t] = W1[t];
  if (t < 32) {
    sb1[t] = b1[t]; sg1[t] = g1[t]; sbe1[t] = be1[t];
    sb2[t] = b2[t]; sg2[t] = g2[t]; sbe2[t] = be2[t];
  }
  sb3[t] = b3[t];
#pragma unroll
  for (int i = 0; i < 4; ++i) {
    int idx = i * 256 + t;                 // idx = j*32+k
    sW2T[idx] = W2[(idx & 31) * 32 + (idx >> 5)];
  }
#pragma unroll
  for (int i = 0; i < 32; ++i) {
    int idx = i * 256 + t;                 // idx = j*32+k
    sW3T[idx] = W3[(idx & 31) * 256 + (idx >> 5)];
  }
  __syncthreads();

  const int stride = gridDim.x * blockDim.x;
  for (int e = blockIdx.x * blockDim.x + t; e < E; e += stride) {
    const float x0 = coords[3 * e + 0];
    const float x1 = coords[3 * e + 1];
    const float x2 = coords[3 * e + 2];

    // Layer 1: 3 -> 32, LN, ReLU
    float h[32];
#pragma unroll
    for (int j = 0; j < 32; ++j)
      h[j] = sb1[j] + x0 * sW1[j] + x1 * sW1[32 + j] + x2 * sW1[64 + j];
    ln_relu(h, sg1, sbe1);

    // Layer 2: 32 -> 32, LN, ReLU (unroll 4: bound load-hoist pressure)
    float h2[32];
#pragma unroll 4
    for (int j = 0; j < 32; ++j) {
      float a = sb2[j];
      const float4* r = (const float4*)&sW2T[j * 32];
#pragma unroll
      for (int k = 0; k < 8; ++k) {
        float4 w = r[k];
        a += h[4 * k + 0] * w.x + h[4 * k + 1] * w.y +
             h[4 * k + 2] * w.z + h[4 * k + 3] * w.w;
      }
      h2[j] = a;
    }
    ln_relu(h2, sg2, sbe2);

    // Gather f (16 floats)
    const int ie = in_edges[e];
    const float4* fp = (const float4*)(edge_features + (size_t)ie * 16);
    float4 f0 = fp[0], f1 = fp[1], f2 = fp[2], f3 = fp[3];
    float f[16] = {f0.x, f0.y, f0.z, f0.w, f1.x, f1.y, f1.z, f1.w,
                   f2.x, f2.y, f2.z, f2.w, f3.x, f3.y, f3.z, f3.w};

    const int oe = out_edges[e];
    if (SCATTER_MODE == 0) {
      int pos = atomicAdd(&cursor[oe], 1);
      bucket[pos] = e;
    }

    // Layer 3 (32 -> 256) fused with tanh + per-edge matvec.
    // o-loop pinned rolled: body is 16 fully-unrolled i-iters (f[i]/h2[.]
    // statically indexed -- runtime indexing would go to scratch).
#pragma unroll 1
    for (int o = 0; o < 16; ++o) {
      float a = 0.f;
#pragma unroll
      for (int i = 0; i < 16; ++i) {
        const int j = o * 16 + i;
        const float4* r = (const float4*)&sW3T[j * 32];
        float acc = sb3[j];
#pragma unroll
        for (int k = 0; k < 8; ++k) {
          float4 w = r[k];
          acc += h2[4 * k + 0] * w.x + h2[4 * k + 1] * w.y +
                 h2[4 * k + 2] * w.z + h2[4 * k + 3] * w.w;
        }
        a += f[i] * fast_tanh(acc);
      }
      if (SCATTER_MODE == 0) {
        out_ch[(size_t)e * 16 + o] = a;    // streamed, no atomics
      } else {
        atomicAdd(&out_ch[(size_t)oe * 16 + o], a);
      }
    }
    if (SCATTER_MODE == 1) atomicAdd(&bucket[oe], 1);
  }
}

// ---------------- per-node reduce (CSR path) ----------------

__global__ __launch_bounds__(256)
void nf_reduce(const float* __restrict__ out_ch, const int* __restrict__ bucket,
               const int* __restrict__ counts, const int* __restrict__ offsets,
               float* __restrict__ out, int N) {
  const int gid = blockIdx.x * 16 + (threadIdx.x >> 4);  // node
  const int o   = threadIdx.x & 15;                      // channel
  if (gid >= N) return;
  const int deg = counts[gid];
  const int off = offsets[gid];
  float acc = 0.f;
  for (int d = 0; d < deg; ++d) {
    int eid = bucket[off + d];
    acc += out_ch[(size_t)eid * 16 + o];
  }
  out[(size_t)gid * 16 + o] = acc / fmaxf((float)deg, 1.0f);
}

// fallback divide
__global__ void nf_final(float* __restrict__ out, const int* __restrict__ counts, int n) {
  int i = blockIdx.x * blockDim.x + threadIdx.x;
  if (i < n) {
    float c = (float)counts[i >> 4];
    out[i] = out[i] / fmaxf(c, 1.0f);
  }
}

extern "C" void kernel_launch(void* const* d_in, const int* in_sizes, int n_in,
                              void* d_out, int out_size, void* d_ws, size_t ws_size,
                              hipStream_t stream) {
  const int*   in_edges  = (const int*)d_in[0];
  const int*   out_edges = (const int*)d_in[1];
  const float* ef        = (const float*)d_in[2];
  const float* coords    = (const float*)d_in[3];
  const float* W1  = (const float*)d_in[4];
  const float* b1  = (const float*)d_in[5];
  const float* g1  = (const float*)d_in[6];
  const float* be1 = (const float*)d_in[7];
  const float* W2  = (const float*)d_in[8];
  const float* b2  = (const float*)d_in[9];
  const float* g2  = (const float*)d_in[10];
  const float* be2 = (const float*)d_in[11];
  const float* W3  = (const float*)d_in[12];
  const float* b3  = (const float*)d_in[13];

  const int E = in_sizes[0];
  const int N = in_sizes[2] / 16;
  float* out = (float*)d_out;

  // workspace layout (CSR path)
  const size_t need = ((size_t)E * 16 + (size_t)E + 3 * (size_t)N) * 4;

  if (ws_size >= need) {
    float* out_ch  = (float*)d_ws;
    int*   bucket  = (int*)(out_ch + (size_t)E * 16);
    int*   counts  = bucket + E;
    int*   offsets = counts + N;
    int*   cursor  = offsets + N;

    hipMemsetAsync(counts, 0, (size_t)N * sizeof(int), stream);
    nf_hist<<<1024, 256, 0, stream>>>(out_edges, counts, E);
    nf_scan<<<1, 1024, 0, stream>>>(counts, offsets, cursor, N);
    nf_main<0><<<2048, 256, 0, stream>>>(in_edges, out_edges, ef, coords,
                                         W1, b1, g1, be1, W2, b2, g2, be2, W3, b3,
                                         out_ch, bucket, cursor, E);
    nf_reduce<<<(N + 15) / 16, 256, 0, stream>>>(out_ch, bucket, counts, offsets, out, N);
  } else {
    // fallback: round-1 direct-atomic path
    int* counts = (int*)d_ws;
    hipMemsetAsync(out, 0, (size_t)out_size * sizeof(float), stream);
    hipMemsetAsync(counts, 0, (size_t)N * sizeof(int), stream);
    nf_main<1><<<2048, 256, 0, stream>>>(in_edges, out_edges, ef, coords,
                                         W1, b1, g1, be1, W2, b2, g2, be2, W3, b3,
                                         out, counts, nullptr, E);
    nf_final<<<(out_size + 255) / 256, 256, 0, stream>>>(out, counts, out_size);
  }
}

// Round 4
// 392.809 us; speedup vs baseline: 4.9309x; 2.6594x over previous
//
#include <hip/hip_runtime.h>

// NeuralFieldCosmo — R4: fragment-resident MFMA formulation.
// Wave = 16 edges (edge = lane&15 as MFMA tile column). Channels live in
// lane-quads matching the 16x16x16 bf16 MFMA C-layout (row=4q+reg), which is
// identical to the A/B k-mapping (k=4q+j), so LN outputs feed the next GEMM's
// B-fragment with zero data movement. No __shared__ at all.
// Scatter: CSR via hist -> wave-scan alloc (disjoint ranges, order-free) ->
// bucket fill -> per-node reduce.

typedef __attribute__((ext_vector_type(4))) short short4v;   // 4 bf16
typedef __attribute__((ext_vector_type(4))) float float4v;

constexpr float LN_EPS   = 1e-5f;
constexpr float LOG2E_X2 = 2.8853900817779268f;  // 2*log2(e)

__device__ __forceinline__ float fast_tanh(float x) {
  float e = __builtin_amdgcn_exp2f(x * LOG2E_X2);
  return 1.0f - 2.0f * __builtin_amdgcn_rcpf(e + 1.0f);
}

// RNE float -> bf16 bits
__device__ __forceinline__ unsigned f2bf(float x) {
  unsigned u = __builtin_bit_cast(unsigned, x);
  u += 0x7FFFu + ((u >> 16) & 1u);
  return u >> 16;
}
__device__ __forceinline__ float bflo2f(unsigned u) {
  return __builtin_bit_cast(float, u << 16);
}
__device__ __forceinline__ float bfhi2f(unsigned u) {
  return __builtin_bit_cast(float, u & 0xFFFF0000u);
}

__device__ __forceinline__ float4v mfma16(short4v a, short4v b, float4v c) {
#if __has_builtin(__builtin_amdgcn_mfma_f32_16x16x16bf16_1k)
  return __builtin_amdgcn_mfma_f32_16x16x16bf16_1k(a, b, c, 0, 0, 0);
#else
  float4v d;
  asm volatile("v_mfma_f32_16x16x16_bf16 %0, %1, %2, %3\n\ts_nop 7\n\ts_nop 7"
               : "=&v"(d) : "v"(a), "v"(b), "v"(c));
  return d;
#endif
}

// LN over 32 channels (8 per lane, spread across quads) + affine + relu,
// packed to the two K-half bf16 B-fragments.
__device__ __forceinline__ void ln_relu_pack(const float* hv, const float* g,
                                             const float* be, short4v* bh) {
  float sum = 0.f;
#pragma unroll
  for (int s = 0; s < 8; ++s) sum += hv[s];
  sum += __shfl_xor(sum, 16);
  sum += __shfl_xor(sum, 32);
  const float m = sum * (1.0f / 32.0f);
  float var = 0.f;
#pragma unroll
  for (int s = 0; s < 8; ++s) { float d = hv[s] - m; var += d * d; }
  var += __shfl_xor(var, 16);
  var += __shfl_xor(var, 32);
  const float rs = rsqrtf(var * (1.0f / 32.0f) + LN_EPS);
#pragma unroll
  for (int h = 0; h < 2; ++h) {
    short4v v;
#pragma unroll
    for (int j = 0; j < 4; ++j) {
      const int s = h * 4 + j;
      float y = (hv[s] - m) * rs * g[s] + be[s];
      v[j] = (short)f2bf(fmaxf(y, 0.f));
    }
    bh[h] = v;
  }
}

// ---------------- CSR build ----------------

__global__ void nf_hist(const int* __restrict__ out_edges, int* __restrict__ counts, int E) {
  int stride = gridDim.x * blockDim.x;
  for (int e = blockIdx.x * blockDim.x + threadIdx.x; e < E; e += stride)
    atomicAdd(&counts[out_edges[e]], 1);
}

// disjoint-range allocation (order-free "scan"): wave-local scan + one atomic/wave
__global__ void nf_alloc(const int* __restrict__ counts, int* __restrict__ offsets,
                         int* __restrict__ cursor, int* __restrict__ total, int N) {
  const int i = blockIdx.x * blockDim.x + threadIdx.x;
  const int lane = threadIdx.x & 63;
  int c = (i < N) ? counts[i] : 0;
  int sc = c;  // inclusive wave scan
#pragma unroll
  for (int d = 1; d < 64; d <<= 1) {
    int v = __shfl_up(sc, d);
    if (lane >= d) sc += v;
  }
  const int excl = sc - c;
  const int wtot = __shfl(sc, 63);
  int base = 0;
  if (lane == 0) base = atomicAdd(total, wtot);
  base = __shfl(base, 0);
  if (i < N) {
    offsets[i] = base + excl;
    cursor[i]  = base + excl;
  }
}

// ---------------- main compute ----------------
// SCATTER_MODE: 0 = CSR (stream out_ch + bucket), 1 = direct atomics fallback

template <int SCATTER_MODE>
__global__ __launch_bounds__(256, 2)
void nf_main(const int* __restrict__ in_edges,
             const int* __restrict__ out_edges,
             const float* __restrict__ ef,
             const float* __restrict__ coords,
             const float* __restrict__ W1, const float* __restrict__ b1,
             const float* __restrict__ g1, const float* __restrict__ be1,
             const float* __restrict__ W2, const float* __restrict__ b2,
             const float* __restrict__ g2, const float* __restrict__ be2,
             const float* __restrict__ W3, const float* __restrict__ b3,
             float* __restrict__ out_ch,  // mode0: [E][16] ; mode1: sums (d_out)
             int* __restrict__ bucket,    // mode0: [E]     ; mode1: counts
             int* __restrict__ cursor,    // mode0: [N]
             int E, int ntiles)
{
  const int l    = threadIdx.x & 63;
  const int q    = l >> 4;     // lane quad: channel/row group
  const int ecol = l & 15;     // edge column within tile
  const int gwave  = (blockIdx.x * blockDim.x + threadIdx.x) >> 6;
  const int nwaves = (gridDim.x * blockDim.x) >> 6;

  // ---- preload per-lane constant fragments (once per wave) ----
  // lane's 8 channels: ch = 4q + (s&3) + 16*(s>>2)
  float w1f[3][8], b1f[8], g1f[8], be1f[8], b2f[8], g2f[8], be2f[8];
#pragma unroll
  for (int s = 0; s < 8; ++s) {
    const int ch = 4 * q + (s & 3) + 16 * (s >> 2);
    w1f[0][s] = W1[ch]; w1f[1][s] = W1[32 + ch]; w1f[2][s] = W1[64 + ch];
    b1f[s] = b1[ch]; g1f[s] = g1[ch]; be1f[s] = be1[ch];
    b2f[s] = b2[ch]; g2f[s] = g2[ch]; be2f[s] = be2[ch];
  }
  // L2 A-frags: A'[m=ch_out][k=ch_in] = W2[k][m]; m = ecol+16*t2, k = 4q+j+16h
  short4v a2[2][2];
#pragma unroll
  for (int t2 = 0; t2 < 2; ++t2)
#pragma unroll
    for (int h = 0; h < 2; ++h) {
      short4v v;
#pragma unroll
      for (int j = 0; j < 4; ++j)
        v[j] = (short)f2bf(W2[(4 * q + j + 16 * h) * 32 + ecol + 16 * t2]);
      a2[t2][h] = v;
    }
  // L3 A-frags: A'[m=i][k=ch2] = W3[ch2][o*16+i]; m = ecol, k = 4q+j+16h
  short4v a3[16][2];
  unsigned b3p[16][2];  // b3[o*16 + 4q + r] packed bf16 pairs
#pragma unroll
  for (int o = 0; o < 16; ++o) {
#pragma unroll
    for (int h = 0; h < 2; ++h) {
      short4v v;
#pragma unroll
      for (int j = 0; j < 4; ++j)
        v[j] = (short)f2bf(W3[(4 * q + j + 16 * h) * 256 + o * 16 + ecol]);
      a3[o][h] = v;
    }
    b3p[o][0] = f2bf(b3[o * 16 + 4 * q + 0]) | (f2bf(b3[o * 16 + 4 * q + 1]) << 16);
    b3p[o][1] = f2bf(b3[o * 16 + 4 * q + 2]) | (f2bf(b3[o * 16 + 4 * q + 3]) << 16);
  }

  for (int tile = gwave; tile < ntiles; tile += nwaves) {
    const int  eIdx  = tile * 16 + ecol;
    const bool valid = eIdx < E;
    const int  eS    = valid ? eIdx : E - 1;

    // gathers for this tile (issued early; consumed ~1.5K cycles later)
    const int ie = in_edges[eS];
    const float4v f4 = *(const float4v*)(ef + (size_t)ie * 16 + 4 * q);
    const float x0 = coords[3 * eS], x1 = coords[3 * eS + 1], x2 = coords[3 * eS + 2];

    // L1 (f32, in-fragment): h[ch = 4q+(s&3)+16(s>>2)][edge = ecol]
    float hv[8];
#pragma unroll
    for (int s = 0; s < 8; ++s)
      hv[s] = b1f[s] + x0 * w1f[0][s] + x1 * w1f[1][s] + x2 * w1f[2][s];

    short4v bh[2];
    ln_relu_pack(hv, g1f, be1f, bh);   // -> L2 B-frags

    // L2 GEMM: two 16-wide ch_out tiles, K=32 via two K-halves
#pragma unroll
    for (int t2 = 0; t2 < 2; ++t2) {
      float4v c;
      c[0] = b2f[t2 * 4 + 0]; c[1] = b2f[t2 * 4 + 1];
      c[2] = b2f[t2 * 4 + 2]; c[3] = b2f[t2 * 4 + 3];
      c = mfma16(a2[t2][0], bh[0], c);
      c = mfma16(a2[t2][1], bh[1], c);
      hv[t2 * 4 + 0] = c[0]; hv[t2 * 4 + 1] = c[1];
      hv[t2 * 4 + 2] = c[2]; hv[t2 * 4 + 3] = c[3];
    }

    ln_relu_pack(hv, g2f, be2f, bh);   // -> L3 B-frags

    // L3 GEMM (16 o-tiles) fused with tanh + f-contraction
    float p[16];
#pragma unroll
    for (int o = 0; o < 16; ++o) {
      float4v c;
      c[0] = bflo2f(b3p[o][0]); c[1] = bfhi2f(b3p[o][0]);
      c[2] = bflo2f(b3p[o][1]); c[3] = bfhi2f(b3p[o][1]);
      c = mfma16(a3[o][0], bh[0], c);
      c = mfma16(a3[o][1], bh[1], c);
      p[o] = f4[0] * fast_tanh(c[0]) + f4[1] * fast_tanh(c[1])
           + f4[2] * fast_tanh(c[2]) + f4[3] * fast_tanh(c[3]);
    }
    // reduce quad partials (i-groups) -> full out_ch[e][o] in every lane
#pragma unroll
    for (int o = 0; o < 16; ++o) {
      p[o] += __shfl_xor(p[o], 16);
      p[o] += __shfl_xor(p[o], 32);
    }

    if (SCATTER_MODE == 0) {
      if (q == 0 && valid) {
        float4v* dst = (float4v*)(out_ch + (size_t)eIdx * 16);
        float4v s0 = {p[0], p[1], p[2], p[3]};
        float4v s1 = {p[4], p[5], p[6], p[7]};
        float4v s2 = {p[8], p[9], p[10], p[11]};
        float4v s3 = {p[12], p[13], p[14], p[15]};
        dst[0] = s0; dst[1] = s1; dst[2] = s2; dst[3] = s3;
        const int oe  = out_edges[eIdx];
        const int pos = atomicAdd(&cursor[oe], 1);
        bucket[pos] = eIdx;
      }
    } else {
      if (q == 0 && valid) {
        const int oe = out_edges[eIdx];
#pragma unroll
        for (int o = 0; o < 16; ++o)
          atomicAdd(&out_ch[(size_t)oe * 16 + o], p[o]);
        atomicAdd(&bucket[oe], 1);
      }
    }
  }
}

// ---------------- per-node reduce (CSR path) ----------------

__global__ __launch_bounds__(256)
void nf_reduce(const float* __restrict__ out_ch, const int* __restrict__ bucket,
               const int* __restrict__ counts, const int* __restrict__ offsets,
               float* __restrict__ out, int N) {
  const int gid = blockIdx.x * 16 + (threadIdx.x >> 4);
  const int o   = threadIdx.x & 15;
  if (gid >= N) return;
  const int deg = counts[gid];
  const int off = offsets[gid];
  float acc = 0.f;
  for (int d = 0; d < deg; ++d) {
    int eid = bucket[off + d];
    acc += out_ch[(size_t)eid * 16 + o];
  }
  out[(size_t)gid * 16 + o] = acc / fmaxf((float)deg, 1.0f);
}

// fallback divide
__global__ void nf_final(float* __restrict__ out, const int* __restrict__ counts, int n) {
  int i = blockIdx.x * blockDim.x + threadIdx.x;
  if (i < n) {
    float c = (float)counts[i >> 4];
    out[i] = out[i] / fmaxf(c, 1.0f);
  }
}

extern "C" void kernel_launch(void* const* d_in, const int* in_sizes, int n_in,
                              void* d_out, int out_size, void* d_ws, size_t ws_size,
                              hipStream_t stream) {
  const int*   in_edges  = (const int*)d_in[0];
  const int*   out_edges = (const int*)d_in[1];
  const float* ef        = (const float*)d_in[2];
  const float* coords    = (const float*)d_in[3];
  const float* W1  = (const float*)d_in[4];
  const float* b1  = (const float*)d_in[5];
  const float* g1  = (const float*)d_in[6];
  const float* be1 = (const float*)d_in[7];
  const float* W2  = (const float*)d_in[8];
  const float* b2  = (const float*)d_in[9];
  const float* g2  = (const float*)d_in[10];
  const float* be2 = (const float*)d_in[11];
  const float* W3  = (const float*)d_in[12];
  const float* b3  = (const float*)d_in[13];

  const int E = in_sizes[0];
  const int N = in_sizes[2] / 16;
  const int ntiles = (E + 15) / 16;
  float* out = (float*)d_out;

  // ws layout: out_ch [16E f32] | bucket [E] | counts [N] | offsets [N] | cursor [N] | total [1]
  const size_t need = ((size_t)E * 16 + (size_t)E + 3 * (size_t)N + 1) * 4;

  if (ws_size >= need) {
    float* out_chv = (float*)d_ws;
    int*   bucket  = (int*)(out_chv + (size_t)E * 16);
    int*   counts  = bucket + E;
    int*   offsets = counts + N;
    int*   cursor  = offsets + N;
    int*   total   = cursor + N;

    hipMemsetAsync(counts, 0, ((size_t)3 * N + 1) * sizeof(int), stream);
    nf_hist<<<1024, 256, 0, stream>>>(out_edges, counts, E);
    nf_alloc<<<(N + 255) / 256, 256, 0, stream>>>(counts, offsets, cursor, total, N);
    nf_main<0><<<1024, 256, 0, stream>>>(in_edges, out_edges, ef, coords,
                                         W1, b1, g1, be1, W2, b2, g2, be2, W3, b3,
                                         out_chv, bucket, cursor, E, ntiles);
    nf_reduce<<<(N + 15) / 16, 256, 0, stream>>>(out_chv, bucket, counts, offsets, out, N);
  } else {
    // fallback: direct atomics
    int* counts = (int*)d_ws;
    hipMemsetAsync(out, 0, (size_t)out_size * sizeof(float), stream);
    hipMemsetAsync(counts, 0, (size_t)N * sizeof(int), stream);
    nf_main<1><<<1024, 256, 0, stream>>>(in_edges, out_edges, ef, coords,
                                         W1, b1, g1, be1, W2, b2, g2, be2, W3, b3,
                                         out, counts, nullptr, E, ntiles);
    nf_final<<<(out_size + 255) / 256, 256, 0, stream>>>(out, counts, out_size);
  }
}